// Round 2
// baseline (1609.528 us; speedup 1.0000x reference)
//
#include <hip/hip_runtime.h>

typedef unsigned short u16;
typedef unsigned int   u32;
typedef __attribute__((ext_vector_type(8))) short bf16x8;
typedef __attribute__((ext_vector_type(4))) float f32x4;

#define ATT_EPS 1e-6f
#define LN_EPS  1e-5f
#define MFMA16  __builtin_amdgcn_mfma_f32_16x16x32_bf16

__device__ __forceinline__ float bflo(u32 u){ return __uint_as_float(u << 16); }
__device__ __forceinline__ float bfhi(u32 u){ return __uint_as_float(u & 0xffff0000u); }
__device__ __forceinline__ u16 f2b(float f){
  u32 x = __float_as_uint(f);
  return (u16)((x + 0x7fffu + ((x >> 16) & 1u)) >> 16);   // RNE
}
__device__ __forceinline__ float elup1(float x){ return x > 0.f ? x + 1.f : __expf(x); }
__device__ __forceinline__ bf16x8 as_bf(uint4 u){ union { uint4 a; bf16x8 b; } c; c.a = u; return c.b; }
__device__ __forceinline__ uint2 pack4(float a, float b, float c, float d){
  return make_uint2((u32)f2b(a) | ((u32)f2b(b) << 16),
                    (u32)f2b(c) | ((u32)f2b(d) << 16));
}

// Swizzled LDS byte-offset helpers (XOR swizzle keeps 8B/16B chunks intact: swz is a multiple of 16).
__device__ __forceinline__ int AO(int l, int cb){ return l*512 + (cb ^ ((l & 7) << 4)); }   // [l][256c] bf16
__device__ __forceinline__ int TO(int c, int sb){ return c*128 + (sb ^ ((c & 7) << 4)); }   // [c][64s] bf16
__device__ __forceinline__ int KVO(int h, int v, int db){ return h*4096 + v*64 + (db ^ ((v & 3) << 4)); } // KVT[h][v][d]

// 4x4 in-register transpose within lane quads (lanes differing in bits 0-1; DPP shuffles).
__device__ __forceinline__ void qtr(float v[4], int qi){
  float x0 = __shfl_xor(v[0],1), x1 = __shfl_xor(v[1],1),
        x2 = __shfl_xor(v[2],1), x3 = __shfl_xor(v[3],1);
  if (qi & 1){ v[0]=x1; v[2]=x3; } else { v[1]=x0; v[3]=x2; }
  float y0 = __shfl_xor(v[0],2), y1 = __shfl_xor(v[1],2),
        y2 = __shfl_xor(v[2],2), y3 = __shfl_xor(v[3],2);
  if (qi & 2){ v[0]=y2; v[1]=y3; } else { v[2]=y0; v[3]=y1; }
}

// ---------------- weight pre-pack: fp32 [K][N] -> bf16 B-fragments ----------------
// Fragment (ks,nt): lane holds B[k = ks*32 + 8*(lane>>4) + j][n = nt*16 + (lane&15)], j=0..7.
__global__ __launch_bounds__(256)
void packw(const float* __restrict__ Wk, const float* __restrict__ Wv,
           const float* __restrict__ Wq, const float* __restrict__ Wm,
           const float* __restrict__ W1, const float* __restrict__ W2,
           uint4* __restrict__ ws)
{
  const int g = blockIdx.x*256 + threadIdx.x;
  const int tile = g >> 6, lane = g & 63;
  const float* src; int Nd, base, tl;
  if      (tile <  128){ src=Wk; Nd=256; base=0;     tl=tile;      }
  else if (tile <  256){ src=Wv; Nd=256; base=8192;  tl=tile-128;  }
  else if (tile <  384){ src=Wq; Nd=256; base=16384; tl=tile-256;  }
  else if (tile <  512){ src=Wm; Nd=256; base=24576; tl=tile-384;  }
  else if (tile < 1024){ src=W1; Nd=512; base=32768; tl=tile-512;  }
  else                 { src=W2; Nd=256; base=65536; tl=tile-1024; }
  const int KS = (tile >= 512) ? 16 : 8;
  const int nt = tl / KS, ks = tl - nt*KS;
  const int k0 = ks*32 + (lane >> 4)*8;
  const int n  = nt*16 + (lane & 15);
  u32 w[4];
  #pragma unroll
  for (int p = 0; p < 4; ++p){
    const u32 lo = f2b(src[(k0 + 2*p    )*Nd + n]);
    const u32 hi = f2b(src[(k0 + 2*p + 1)*Nd + n]);
    w[p] = lo | (hi << 16);
  }
  ws[base + (nt*KS + ks)*64 + lane] = make_uint4(w[0], w[1], w[2], w[3]);
}

// ---------------- main kernel: one block per 8x8 window, 8 waves = 2(M)x4(N) ----------------
__global__ __launch_bounds__(512, 4)
void lgattn_mfma(const float* __restrict__ xg, const uint4* __restrict__ wpk,
                 const float* __restrict__ g1v, const float* __restrict__ b1v,
                 const float* __restrict__ g2v, const float* __restrict__ b2v,
                 float* __restrict__ outg)
{
  __shared__ __align__(16) char  lds0[32768]; // X-stage -> V_T -> Q -> h(halves)
  __shared__ __align__(16) char  lds1[32768]; // K_T(+KVT) -> msg_att -> msg
  __shared__ __align__(16) float ksum[256];
  __shared__ __align__(16) float denb[512];   // [l][h]
  __shared__ __align__(16) float ps[512];     // LN partials [row][wn4][{s,sq}]

  const int t    = threadIdx.x;
  const int lane = t & 63;
  const int wid  = t >> 6;          // 0..7
  const int wm   = wid >> 2, wn = wid & 3;
  const int l15  = lane & 15, g4 = lane >> 4;
  const int qi   = lane & 3,  qq = (lane >> 2) & 3;
  const int rowA = 32*wm;           // wave M base (rows)
  const int wbn  = 4*wn;            // wave N-tile base (4 tiles of 16 = 64 cols)

  const int win = blockIdx.x;
  const int b   = win / 900;
  const int rem = win - b*900;
  const int wh  = rem / 30;
  const int ww  = rem - wh*30;
  const long long rowbase = ((long long)b*240 + wh*8)*240 + ww*8;

  const f32x4 fz = {0.f, 0.f, 0.f, 0.f};

  // ---- P0: stage x -> lds0 bf16 [l][c] (swizzled), coalesced float4 reads
  {
    const int r0 = wid*8, c0 = lane*4;
    #pragma unroll
    for (int i = 0; i < 8; ++i){
      const int l = r0 + i;
      const long long row = rowbase + (l >> 3)*240 + (l & 7);
      const float4 u = *(const float4*)(xg + row*256 + c0);
      *(uint2*)(lds0 + AO(l, c0*2)) = pack4(u.x, u.y, u.z, u.w);
    }
  }
  __syncthreads();

  // ---- P1: X A-fragments -> regs (reused by K,V,Q GEMMs and MLP1 x-part)
  bf16x8 xf[2][8];
  #pragma unroll
  for (int mt = 0; mt < 2; ++mt)
    #pragma unroll
    for (int ks = 0; ks < 8; ++ks)
      xf[mt][ks] = as_bf(*(const uint4*)(lds0 + AO(rowA + mt*16 + l15, ks*64 + g4*16)));
  __syncthreads();

  // ---- P2a: K = elu(x@Wk)+1 -> K_T in lds1 ([c][s])
  {
    f32x4 acc[4][2];
    #pragma unroll
    for (int nt = 0; nt < 4; ++nt){ acc[nt][0] = fz; acc[nt][1] = fz; }
    #pragma unroll
    for (int ks = 0; ks < 8; ++ks)
      #pragma unroll
      for (int nt = 0; nt < 4; ++nt){
        const bf16x8 bv = as_bf(wpk[((wbn + nt)*8 + ks)*64 + lane]);
        acc[nt][0] = MFMA16(xf[0][ks], bv, acc[nt][0], 0, 0, 0);
        acc[nt][1] = MFMA16(xf[1][ks], bv, acc[nt][1], 0, 0, 0);
      }
    #pragma unroll
    for (int nt = 0; nt < 4; ++nt)
      #pragma unroll
      for (int mt = 0; mt < 2; ++mt){
        const int c  = 64*wn + nt*16 + l15;
        const int sb = (rowA + mt*16 + 4*g4)*2;
        *(uint2*)(lds1 + TO(c, sb)) =
          pack4(elup1(acc[nt][mt][0]), elup1(acc[nt][mt][1]),
                elup1(acc[nt][mt][2]), elup1(acc[nt][mt][3]));
      }
  }
  // ---- P2b: V = x@Wv -> V_T in lds0 (X-stage dead; frags held in regs)
  {
    f32x4 acc[4][2];
    #pragma unroll
    for (int nt = 0; nt < 4; ++nt){ acc[nt][0] = fz; acc[nt][1] = fz; }
    #pragma unroll
    for (int ks = 0; ks < 8; ++ks)
      #pragma unroll
      for (int nt = 0; nt < 4; ++nt){
        const bf16x8 bv = as_bf(wpk[8192 + ((wbn + nt)*8 + ks)*64 + lane]);
        acc[nt][0] = MFMA16(xf[0][ks], bv, acc[nt][0], 0, 0, 0);
        acc[nt][1] = MFMA16(xf[1][ks], bv, acc[nt][1], 0, 0, 0);
      }
    #pragma unroll
    for (int nt = 0; nt < 4; ++nt)
      #pragma unroll
      for (int mt = 0; mt < 2; ++mt){
        const int c  = 64*wn + nt*16 + l15;
        const int sb = (rowA + mt*16 + 4*g4)*2;
        *(uint2*)(lds0 + TO(c, sb)) =
          pack4(acc[nt][mt][0], acc[nt][mt][1], acc[nt][mt][2], acc[nt][mt][3]);
      }
  }
  __syncthreads();

  // ---- P4: KV[h] = K_h^T @ V_h (32x32, K=64), one head per wave; Ksum folded in
  {
    const int h = wid;
    f32x4 acc[2][2];
    acc[0][0]=fz; acc[0][1]=fz; acc[1][0]=fz; acc[1][1]=fz;
    uint4 araw[2][2];
    #pragma unroll
    for (int ks = 0; ks < 2; ++ks)
      #pragma unroll
      for (int mt = 0; mt < 2; ++mt)
        araw[ks][mt] = *(const uint4*)(lds1 + TO(h*32 + mt*16 + l15, ks*64 + g4*16));
    #pragma unroll
    for (int ks = 0; ks < 2; ++ks){
      bf16x8 bb[2];
      #pragma unroll
      for (int nt = 0; nt < 2; ++nt)
        bb[nt] = as_bf(*(const uint4*)(lds0 + TO(h*32 + nt*16 + l15, ks*64 + g4*16)));
      #pragma unroll
      for (int mt = 0; mt < 2; ++mt)
        #pragma unroll
        for (int nt = 0; nt < 2; ++nt)
          acc[mt][nt] = MFMA16(as_bf(araw[ks][mt]), bb[nt], acc[mt][nt], 0, 0, 0);
    }
    // Ksum[c] from the same fragments: sum 16 k-values per lane, reduce over g4 groups
    float sm0 = 0.f, sm1 = 0.f;
    #pragma unroll
    for (int ks = 0; ks < 2; ++ks){
      const uint4 u0 = araw[ks][0], u1 = araw[ks][1];
      sm0 += bflo(u0.x)+bfhi(u0.x)+bflo(u0.y)+bfhi(u0.y)
           + bflo(u0.z)+bfhi(u0.z)+bflo(u0.w)+bfhi(u0.w);
      sm1 += bflo(u1.x)+bfhi(u1.x)+bflo(u1.y)+bfhi(u1.y)
           + bflo(u1.z)+bfhi(u1.z)+bflo(u1.w)+bfhi(u1.w);
    }
    sm0 += __shfl_xor(sm0, 16); sm0 += __shfl_xor(sm0, 32);
    sm1 += __shfl_xor(sm1, 16); sm1 += __shfl_xor(sm1, 32);
    if (lane < 16){ ksum[h*32 + l15] = sm0; ksum[h*32 + 16 + l15] = sm1; }
    #pragma unroll
    for (int mt = 0; mt < 2; ++mt)
      #pragma unroll
      for (int nt = 0; nt < 2; ++nt){
        const int v  = nt*16 + l15;
        const int db = (mt*16 + 4*g4)*2;
        *(uint2*)(lds1 + KVO(h, v, db)) =
          pack4(acc[mt][nt][0], acc[mt][nt][1], acc[mt][nt][2], acc[mt][nt][3]);
      }
  }
  __syncthreads();

  // ---- P5: Q = elu(x@Wq)+1 -> lds0 [l][c] (transpose epilogue; V_T dead)
  {
    f32x4 acc[4][2];
    #pragma unroll
    for (int nt = 0; nt < 4; ++nt){ acc[nt][0] = fz; acc[nt][1] = fz; }
    #pragma unroll
    for (int ks = 0; ks < 8; ++ks)
      #pragma unroll
      for (int nt = 0; nt < 4; ++nt){
        const bf16x8 bv = as_bf(wpk[16384 + ((wbn + nt)*8 + ks)*64 + lane]);
        acc[nt][0] = MFMA16(xf[0][ks], bv, acc[nt][0], 0, 0, 0);
        acc[nt][1] = MFMA16(xf[1][ks], bv, acc[nt][1], 0, 0, 0);
      }
    #pragma unroll
    for (int nt = 0; nt < 4; ++nt)
      #pragma unroll
      for (int mt = 0; mt < 2; ++mt){
        float v[4];
        #pragma unroll
        for (int r = 0; r < 4; ++r) v[r] = elup1(acc[nt][mt][r]);
        qtr(v, qi);
        const int l  = rowA + mt*16 + 4*g4 + qi;
        const int cb = (64*wn + nt*16 + 4*qq)*2;
        *(uint2*)(lds0 + AO(l, cb)) = pack4(v[0], v[1], v[2], v[3]);
      }
  }
  // No barrier: Q rows/cols written and consumed by the SAME wave (den + attn A-frags).

  // ---- P6: den[l][h] = eps + Q[l,h*32:]. Ksum[h*32:]  (1 head per lane-half, own rows/heads)
  {
    const int dl = rowA + (lane & 31);
    const int h  = 2*wn + (lane >> 5);
    float s = ATT_EPS;
    #pragma unroll
    for (int j = 0; j < 4; ++j){
      const uint4  qv = *(const uint4*)(lds0 + AO(dl, h*64 + j*16));
      const float4 k0 = *(const float4*)&ksum[h*32 + j*8];
      const float4 k1 = *(const float4*)&ksum[h*32 + j*8 + 4];
      s += bflo(qv.x)*k0.x + bfhi(qv.x)*k0.y + bflo(qv.y)*k0.z + bfhi(qv.y)*k0.w
         + bflo(qv.z)*k1.x + bfhi(qv.z)*k1.y + bflo(qv.w)*k1.z + bfhi(qv.w)*k1.w;
    }
    denb[dl*8 + h] = s;
  }

  // ---- P7: num = Q_h @ KV_h (2 heads/wave), then msg_att = num/den -> lds1 [l][c]
  {
    f32x4 nacc[2][2][2];
    #pragma unroll
    for (int hh = 0; hh < 2; ++hh)
      #pragma unroll
      for (int mt = 0; mt < 2; ++mt)
        #pragma unroll
        for (int nt = 0; nt < 2; ++nt) nacc[hh][mt][nt] = fz;
    #pragma unroll
    for (int hh = 0; hh < 2; ++hh){
      const int h = 2*wn + hh;
      bf16x8 a[2], bb[2];
      #pragma unroll
      for (int mt = 0; mt < 2; ++mt)
        a[mt]  = as_bf(*(const uint4*)(lds0 + AO(rowA + mt*16 + l15, h*64 + g4*16)));
      #pragma unroll
      for (int nt = 0; nt < 2; ++nt)
        bb[nt] = as_bf(*(const uint4*)(lds1 + KVO(h, nt*16 + l15, g4*16)));
      #pragma unroll
      for (int mt = 0; mt < 2; ++mt)
        #pragma unroll
        for (int nt = 0; nt < 2; ++nt)
          nacc[hh][mt][nt] = MFMA16(a[mt], bb[nt], nacc[hh][mt][nt], 0, 0, 0);
    }
    __syncthreads();   // all waves done reading KVT/K_T region before msg_att overwrites lds1
    #pragma unroll
    for (int hh = 0; hh < 2; ++hh){
      const int h = 2*wn + hh;
      #pragma unroll
      for (int mt = 0; mt < 2; ++mt){
        const int   l  = rowA + mt*16 + 4*g4 + qi;
        const float rd = 1.0f / denb[l*8 + h];
        #pragma unroll
        for (int nt = 0; nt < 2; ++nt){
          float v[4];
          #pragma unroll
          for (int r = 0; r < 4; ++r) v[r] = nacc[hh][mt][nt][r];
          qtr(v, qi);
          const int cb = (h*32 + nt*16 + 4*qq)*2;
          *(uint2*)(lds1 + AO(l, cb)) = pack4(v[0]*rd, v[1]*rd, v[2]*rd, v[3]*rd);
        }
      }
    }
  }
  __syncthreads();

  // ---- P8: msg = LN1(msg_att @ Wm) -> lds1 [l][c]
  {
    f32x4 macc[4][2];
    #pragma unroll
    for (int nt = 0; nt < 4; ++nt){ macc[nt][0] = fz; macc[nt][1] = fz; }
    #pragma unroll
    for (int ks = 0; ks < 8; ++ks){
      const bf16x8 a0 = as_bf(*(const uint4*)(lds1 + AO(rowA      + l15, ks*64 + g4*16)));
      const bf16x8 a1 = as_bf(*(const uint4*)(lds1 + AO(rowA + 16 + l15, ks*64 + g4*16)));
      #pragma unroll
      for (int nt = 0; nt < 4; ++nt){
        const bf16x8 bv = as_bf(wpk[24576 + ((wbn + nt)*8 + ks)*64 + lane]);
        macc[nt][0] = MFMA16(a0, bv, macc[nt][0], 0, 0, 0);
        macc[nt][1] = MFMA16(a1, bv, macc[nt][1], 0, 0, 0);
      }
    }
    // LN1 stats: intra-wave (64 cols) via shfl over l15, cross-wn via ps
    float sm[2][4], sv[2][4];
    #pragma unroll
    for (int mt = 0; mt < 2; ++mt)
      #pragma unroll
      for (int r = 0; r < 4; ++r){
        float s = 0.f, q = 0.f;
        #pragma unroll
        for (int nt = 0; nt < 4; ++nt){ const float x = macc[nt][mt][r]; s += x; q += x*x; }
        #pragma unroll
        for (int m = 1; m < 16; m <<= 1){ s += __shfl_xor(s, m); q += __shfl_xor(q, m); }
        sm[mt][r] = s; sv[mt][r] = q;
      }
    if (l15 == 0){
      #pragma unroll
      for (int mt = 0; mt < 2; ++mt)
        #pragma unroll
        for (int r = 0; r < 4; ++r){
          const int row = rowA + mt*16 + 4*g4 + r;
          *(float2*)&ps[(row*4 + wn)*2] = make_float2(sm[mt][r], sv[mt][r]);
        }
    }
    __syncthreads();
    float mean[2][4], rstd[2][4];
    #pragma unroll
    for (int mt = 0; mt < 2; ++mt)
      #pragma unroll
      for (int r = 0; r < 4; ++r){
        const int row = rowA + mt*16 + 4*g4 + r;
        float st = 0.f, qt = 0.f;
        #pragma unroll
        for (int w = 0; w < 4; ++w){
          const float2 p = *(const float2*)&ps[(row*4 + w)*2];
          st += p.x; qt += p.y;
        }
        const float mn = st * (1.f/256.f);
        mean[mt][r] = mn;
        rstd[mt][r] = rsqrtf(qt*(1.f/256.f) - mn*mn + LN_EPS);
      }
    #pragma unroll
    for (int mt = 0; mt < 2; ++mt){
      const int l = rowA + mt*16 + 4*g4 + qi;
      #pragma unroll
      for (int nt = 0; nt < 4; ++nt){
        float v[4];
        #pragma unroll
        for (int r = 0; r < 4; ++r) v[r] = (macc[nt][mt][r] - mean[mt][r]) * rstd[mt][r];
        qtr(v, qi);
        const int c = 64*wn + nt*16 + 4*qq;
        const float4 gg = *(const float4*)(g1v + c);
        const float4 bb = *(const float4*)(b1v + c);
        *(uint2*)(lds1 + AO(l, c*2)) =
          pack4(v[0]*gg.x + bb.x, v[1]*gg.y + bb.y, v[2]*gg.z + bb.z, v[3]*gg.w + bb.w);
      }
    }
  }
  __syncthreads();

  // ---- P9: MLP. h(jt) = relu([x|msg]@W1[:,jt]) -> lds0; oacc += h @ W2[jt]
  f32x4 oacc[4][2];
  #pragma unroll
  for (int nt = 0; nt < 4; ++nt){ oacc[nt][0] = fz; oacc[nt][1] = fz; }

  #pragma unroll
  for (int jt = 0; jt < 2; ++jt){
    f32x4 hacc[4][2];
    #pragma unroll
    for (int nt = 0; nt < 4; ++nt){ hacc[nt][0] = fz; hacc[nt][1] = fz; }
    #pragma unroll
    for (int ks = 0; ks < 8; ++ks)         // x part (k = 0..255), A = held xf
      #pragma unroll
      for (int nt = 0; nt < 4; ++nt){
        const bf16x8 bv = as_bf(wpk[32768 + ((jt*16 + wbn + nt)*16 + ks)*64 + lane]);
        hacc[nt][0] = MFMA16(xf[0][ks], bv, hacc[nt][0], 0, 0, 0);
        hacc[nt][1] = MFMA16(xf[1][ks], bv, hacc[nt][1], 0, 0, 0);
      }
    #pragma unroll
    for (int ks = 0; ks < 8; ++ks){        // msg part (k = 256..511), A from lds1
      const bf16x8 a0 = as_bf(*(const uint4*)(lds1 + AO(rowA      + l15, ks*64 + g4*16)));
      const bf16x8 a1 = as_bf(*(const uint4*)(lds1 + AO(rowA + 16 + l15, ks*64 + g4*16)));
      #pragma unroll
      for (int nt = 0; nt < 4; ++nt){
        const bf16x8 bv = as_bf(wpk[32768 + ((jt*16 + wbn + nt)*16 + 8 + ks)*64 + lane]);
        hacc[nt][0] = MFMA16(a0, bv, hacc[nt][0], 0, 0, 0);
        hacc[nt][1] = MFMA16(a1, bv, hacc[nt][1], 0, 0, 0);
      }
    }
    // relu + transpose -> h in lds0
    #pragma unroll
    for (int mt = 0; mt < 2; ++mt){
      const int l = rowA + mt*16 + 4*g4 + qi;
      #pragma unroll
      for (int nt = 0; nt < 4; ++nt){
        float v[4];
        #pragma unroll
        for (int r = 0; r < 4; ++r) v[r] = fmaxf(hacc[nt][mt][r], 0.f);
        qtr(v, qi);
        const int cb = (64*wn + nt*16 + 4*qq)*2;
        *(uint2*)(lds0 + AO(l, cb)) = pack4(v[0], v[1], v[2], v[3]);
      }
    }
    __syncthreads();
    #pragma unroll
    for (int ks = 0; ks < 8; ++ks){
      const bf16x8 a0 = as_bf(*(const uint4*)(lds0 + AO(rowA      + l15, ks*64 + g4*16)));
      const bf16x8 a1 = as_bf(*(const uint4*)(lds0 + AO(rowA + 16 + l15, ks*64 + g4*16)));
      #pragma unroll
      for (int nt = 0; nt < 4; ++nt){
        const bf16x8 bv = as_bf(wpk[65536 + ((wbn + nt)*16 + jt*8 + ks)*64 + lane]);
        oacc[nt][0] = MFMA16(a0, bv, oacc[nt][0], 0, 0, 0);
        oacc[nt][1] = MFMA16(a1, bv, oacc[nt][1], 0, 0, 0);
      }
    }
    if (jt == 0) __syncthreads();          // protect h overwrite in jt=1
  }

  // ---- P10: LN2 + residual + store
  {
    float sm[2][4], sv[2][4];
    #pragma unroll
    for (int mt = 0; mt < 2; ++mt)
      #pragma unroll
      for (int r = 0; r < 4; ++r){
        float s = 0.f, q = 0.f;
        #pragma unroll
        for (int nt = 0; nt < 4; ++nt){ const float x = oacc[nt][mt][r]; s += x; q += x*x; }
        #pragma unroll
        for (int m = 1; m < 16; m <<= 1){ s += __shfl_xor(s, m); q += __shfl_xor(q, m); }
        sm[mt][r] = s; sv[mt][r] = q;
      }
    // ps last read in P8, >=3 barriers ago -> safe to overwrite
    if (l15 == 0){
      #pragma unroll
      for (int mt = 0; mt < 2; ++mt)
        #pragma unroll
        for (int r = 0; r < 4; ++r){
          const int row = rowA + mt*16 + 4*g4 + r;
          *(float2*)&ps[(row*4 + wn)*2] = make_float2(sm[mt][r], sv[mt][r]);
        }
    }
    __syncthreads();
    float mean[2][4], rstd[2][4];
    #pragma unroll
    for (int mt = 0; mt < 2; ++mt)
      #pragma unroll
      for (int r = 0; r < 4; ++r){
        const int row = rowA + mt*16 + 4*g4 + r;
        float st = 0.f, qt = 0.f;
        #pragma unroll
        for (int w = 0; w < 4; ++w){
          const float2 p = *(const float2*)&ps[(row*4 + w)*2];
          st += p.x; qt += p.y;
        }
        const float mn = st * (1.f/256.f);
        mean[mt][r] = mn;
        rstd[mt][r] = rsqrtf(qt*(1.f/256.f) - mn*mn + LN_EPS);
      }
    #pragma unroll
    for (int mt = 0; mt < 2; ++mt){
      const int l = rowA + mt*16 + 4*g4 + qi;
      const long long row = rowbase + (l >> 3)*240 + (l & 7);
      #pragma unroll
      for (int nt = 0; nt < 4; ++nt){
        float v[4];
        #pragma unroll
        for (int r = 0; r < 4; ++r) v[r] = (oacc[nt][mt][r] - mean[mt][r]) * rstd[mt][r];
        qtr(v, qi);
        const int c = 64*wn + nt*16 + 4*qq;
        const float4 gg = *(const float4*)(g2v + c);
        const float4 bb = *(const float4*)(b2v + c);
        const float4 xu = *(const float4*)(xg + row*256 + c);
        float4 st;
        st.x = v[0]*gg.x + bb.x + xu.x;
        st.y = v[1]*gg.y + bb.y + xu.y;
        st.z = v[2]*gg.z + bb.z + xu.z;
        st.w = v[3]*gg.w + bb.w + xu.w;
        *(float4*)(outg + row*256 + c) = st;
      }
    }
  }
}

extern "C" void kernel_launch(void* const* d_in, const int* in_sizes, int n_in,
                              void* d_out, int out_size, void* d_ws, size_t ws_size,
                              hipStream_t stream) {
  const float* xg = (const float*)d_in[0];
  const float* Wq = (const float*)d_in[1];
  const float* Wk = (const float*)d_in[2];
  const float* Wv = (const float*)d_in[3];
  const float* Wm = (const float*)d_in[4];
  const float* W1 = (const float*)d_in[5];
  const float* W2 = (const float*)d_in[6];
  const float* g1 = (const float*)d_in[7];
  const float* b1 = (const float*)d_in[8];
  const float* g2 = (const float*)d_in[9];
  const float* b2 = (const float*)d_in[10];

  uint4* wpk = (uint4*)d_ws;                       // needs 1.25 MB of workspace
  packw<<<dim3(320), dim3(256), 0, stream>>>(Wk, Wv, Wq, Wm, W1, W2, wpk);

  const int B = in_sizes[0] / (240 * 240 * 256);
  lgattn_mfma<<<dim3(B * 900), dim3(512), 0, stream>>>(xg, wpk, g1, b1, g2, b2, (float*)d_out);
}

// Round 3
// 1200.007 us; speedup vs baseline: 1.3413x; 1.3413x over previous
//
#include <hip/hip_runtime.h>

typedef unsigned short u16;
typedef unsigned int   u32;
typedef __attribute__((ext_vector_type(8))) short bf16x8;
typedef __attribute__((ext_vector_type(4))) float f32x4;

#define ATT_EPS 1e-6f
#define LN_EPS  1e-5f
#define MFMA16  __builtin_amdgcn_mfma_f32_16x16x32_bf16

__device__ __forceinline__ float bflo(u32 u){ return __uint_as_float(u << 16); }
__device__ __forceinline__ float bfhi(u32 u){ return __uint_as_float(u & 0xffff0000u); }
__device__ __forceinline__ u16 f2b(float f){
  u32 x = __float_as_uint(f);
  return (u16)((x + 0x7fffu + ((x >> 16) & 1u)) >> 16);   // RNE
}
__device__ __forceinline__ float elup1(float x){ return x > 0.f ? x + 1.f : __expf(x); }
__device__ __forceinline__ bf16x8 as_bf(uint4 u){ union { uint4 a; bf16x8 b; } c; c.a = u; return c.b; }
__device__ __forceinline__ uint2 pack4(float a, float b, float c, float d){
  return make_uint2((u32)f2b(a) | ((u32)f2b(b) << 16),
                    (u32)f2b(c) | ((u32)f2b(d) << 16));
}

// Swizzled LDS byte-offset helpers (XOR swizzle keeps 8B/16B chunks intact: swz is a multiple of 16).
__device__ __forceinline__ int AO(int l, int cb){ return l*512 + (cb ^ ((l & 7) << 4)); }   // [l][256c] bf16
__device__ __forceinline__ int TO(int c, int sb){ return c*128 + (sb ^ ((c & 7) << 4)); }   // [c][64s] bf16
__device__ __forceinline__ int KVO(int h, int v, int db){ return h*4096 + v*64 + (db ^ ((v & 3) << 4)); } // KVT[h][v][d]

// 4x4 in-register transpose within lane quads (lanes differing in bits 0-1; DPP shuffles).
__device__ __forceinline__ void qtr(float v[4], int qi){
  float x0 = __shfl_xor(v[0],1), x1 = __shfl_xor(v[1],1),
        x2 = __shfl_xor(v[2],1), x3 = __shfl_xor(v[3],1);
  if (qi & 1){ v[0]=x1; v[2]=x3; } else { v[1]=x0; v[3]=x2; }
  float y0 = __shfl_xor(v[0],2), y1 = __shfl_xor(v[1],2),
        y2 = __shfl_xor(v[2],2), y3 = __shfl_xor(v[3],2);
  if (qi & 2){ v[0]=y2; v[1]=y3; } else { v[2]=y0; v[3]=y1; }
}

// ---------------- weight pre-pack: fp32 [K][N] -> bf16 B-fragments ----------------
// Fragment (ks,nt): lane holds B[k = ks*32 + 8*(lane>>4) + j][n = nt*16 + (lane&15)], j=0..7.
__global__ __launch_bounds__(256)
void packw(const float* __restrict__ Wk, const float* __restrict__ Wv,
           const float* __restrict__ Wq, const float* __restrict__ Wm,
           const float* __restrict__ W1, const float* __restrict__ W2,
           uint4* __restrict__ ws)
{
  const int g = blockIdx.x*256 + threadIdx.x;
  const int tile = g >> 6, lane = g & 63;
  const float* src; int Nd, base, tl;
  if      (tile <  128){ src=Wk; Nd=256; base=0;     tl=tile;      }
  else if (tile <  256){ src=Wv; Nd=256; base=8192;  tl=tile-128;  }
  else if (tile <  384){ src=Wq; Nd=256; base=16384; tl=tile-256;  }
  else if (tile <  512){ src=Wm; Nd=256; base=24576; tl=tile-384;  }
  else if (tile < 1024){ src=W1; Nd=512; base=32768; tl=tile-512;  }
  else                 { src=W2; Nd=256; base=65536; tl=tile-1024; }
  const int KS = (tile >= 512) ? 16 : 8;
  const int nt = tl / KS, ks = tl - nt*KS;
  const int k0 = ks*32 + (lane >> 4)*8;
  const int n  = nt*16 + (lane & 15);
  u32 w[4];
  #pragma unroll
  for (int p = 0; p < 4; ++p){
    const u32 lo = f2b(src[(k0 + 2*p    )*Nd + n]);
    const u32 hi = f2b(src[(k0 + 2*p + 1)*Nd + n]);
    w[p] = lo | (hi << 16);
  }
  ws[base + (nt*KS + ks)*64 + lane] = make_uint4(w[0], w[1], w[2], w[3]);
}

// ---------------- main kernel: one block per 8x8 window, 8 waves = 2(M)x4(N) ----------------
// __launch_bounds__(512, 2): empirically gives the allocator ~128 VGPR (the (512,4) variant
// forced 64 VGPR -> catastrophic scratch spills: WRITE_SIZE 0.34->1.64 GB). HW occupancy is
// LDS-capped at 2 blocks/CU either way (70.6 KB), and 128 VGPR still admits 16 waves/CU.
__global__ __launch_bounds__(512, 2)
void lgattn_mfma(const float* __restrict__ xg, const uint4* __restrict__ wpk,
                 const float* __restrict__ g1v, const float* __restrict__ b1v,
                 const float* __restrict__ g2v, const float* __restrict__ b2v,
                 float* __restrict__ outg)
{
  __shared__ __align__(16) char  lds0[32768]; // X-stage -> V_T -> Q -> h(halves)
  __shared__ __align__(16) char  lds1[32768]; // K_T(+KVT) -> msg_att -> msg
  __shared__ __align__(16) float ksum[256];
  __shared__ __align__(16) float denb[512];   // [l][h]
  __shared__ __align__(16) float ps[512];     // LN partials [row][wn4][{s,sq}]

  const int t    = threadIdx.x;
  const int lane = t & 63;
  const int wid  = t >> 6;          // 0..7
  const int wm   = wid >> 2, wn = wid & 3;
  const int l15  = lane & 15, g4 = lane >> 4;
  const int qi   = lane & 3,  qq = (lane >> 2) & 3;
  const int rowA = 32*wm;           // wave M base (rows)
  const int wbn  = 4*wn;            // wave N-tile base (4 tiles of 16 = 64 cols)

  const int win = blockIdx.x;
  const int b   = win / 900;
  const int rem = win - b*900;
  const int wh  = rem / 30;
  const int ww  = rem - wh*30;
  const long long rowbase = ((long long)b*240 + wh*8)*240 + ww*8;

  const f32x4 fz = {0.f, 0.f, 0.f, 0.f};

  // ---- P0: stage x -> lds0 bf16 [l][c] (swizzled), coalesced float4 reads
  {
    const int r0 = wid*8, c0 = lane*4;
    #pragma unroll
    for (int i = 0; i < 8; ++i){
      const int l = r0 + i;
      const long long row = rowbase + (l >> 3)*240 + (l & 7);
      const float4 u = *(const float4*)(xg + row*256 + c0);
      *(uint2*)(lds0 + AO(l, c0*2)) = pack4(u.x, u.y, u.z, u.w);
    }
  }
  __syncthreads();

  // ---- P1: X A-fragments -> regs (reused by K,V,Q GEMMs and MLP1 x-part)
  bf16x8 xf[2][8];
  #pragma unroll
  for (int mt = 0; mt < 2; ++mt)
    #pragma unroll
    for (int ks = 0; ks < 8; ++ks)
      xf[mt][ks] = as_bf(*(const uint4*)(lds0 + AO(rowA + mt*16 + l15, ks*64 + g4*16)));
  __syncthreads();

  // ---- P2a: K = elu(x@Wk)+1 -> K_T in lds1 ([c][s])
  {
    f32x4 acc[4][2];
    #pragma unroll
    for (int nt = 0; nt < 4; ++nt){ acc[nt][0] = fz; acc[nt][1] = fz; }
    #pragma unroll
    for (int ks = 0; ks < 8; ++ks)
      #pragma unroll
      for (int nt = 0; nt < 4; ++nt){
        const bf16x8 bv = as_bf(wpk[((wbn + nt)*8 + ks)*64 + lane]);
        acc[nt][0] = MFMA16(xf[0][ks], bv, acc[nt][0], 0, 0, 0);
        acc[nt][1] = MFMA16(xf[1][ks], bv, acc[nt][1], 0, 0, 0);
      }
    #pragma unroll
    for (int nt = 0; nt < 4; ++nt)
      #pragma unroll
      for (int mt = 0; mt < 2; ++mt){
        const int c  = 64*wn + nt*16 + l15;
        const int sb = (rowA + mt*16 + 4*g4)*2;
        *(uint2*)(lds1 + TO(c, sb)) =
          pack4(elup1(acc[nt][mt][0]), elup1(acc[nt][mt][1]),
                elup1(acc[nt][mt][2]), elup1(acc[nt][mt][3]));
      }
  }
  // ---- P2b: V = x@Wv -> V_T in lds0 (X-stage dead; frags held in regs)
  {
    f32x4 acc[4][2];
    #pragma unroll
    for (int nt = 0; nt < 4; ++nt){ acc[nt][0] = fz; acc[nt][1] = fz; }
    #pragma unroll
    for (int ks = 0; ks < 8; ++ks)
      #pragma unroll
      for (int nt = 0; nt < 4; ++nt){
        const bf16x8 bv = as_bf(wpk[8192 + ((wbn + nt)*8 + ks)*64 + lane]);
        acc[nt][0] = MFMA16(xf[0][ks], bv, acc[nt][0], 0, 0, 0);
        acc[nt][1] = MFMA16(xf[1][ks], bv, acc[nt][1], 0, 0, 0);
      }
    #pragma unroll
    for (int nt = 0; nt < 4; ++nt)
      #pragma unroll
      for (int mt = 0; mt < 2; ++mt){
        const int c  = 64*wn + nt*16 + l15;
        const int sb = (rowA + mt*16 + 4*g4)*2;
        *(uint2*)(lds0 + TO(c, sb)) =
          pack4(acc[nt][mt][0], acc[nt][mt][1], acc[nt][mt][2], acc[nt][mt][3]);
      }
  }
  __syncthreads();

  // ---- P4: KV[h] = K_h^T @ V_h (32x32, K=64), one head per wave; Ksum folded in
  {
    const int h = wid;
    f32x4 acc[2][2];
    acc[0][0]=fz; acc[0][1]=fz; acc[1][0]=fz; acc[1][1]=fz;
    uint4 araw[2][2];
    #pragma unroll
    for (int ks = 0; ks < 2; ++ks)
      #pragma unroll
      for (int mt = 0; mt < 2; ++mt)
        araw[ks][mt] = *(const uint4*)(lds1 + TO(h*32 + mt*16 + l15, ks*64 + g4*16));
    #pragma unroll
    for (int ks = 0; ks < 2; ++ks){
      bf16x8 bb[2];
      #pragma unroll
      for (int nt = 0; nt < 2; ++nt)
        bb[nt] = as_bf(*(const uint4*)(lds0 + TO(h*32 + nt*16 + l15, ks*64 + g4*16)));
      #pragma unroll
      for (int mt = 0; mt < 2; ++mt)
        #pragma unroll
        for (int nt = 0; nt < 2; ++nt)
          acc[mt][nt] = MFMA16(as_bf(araw[ks][mt]), bb[nt], acc[mt][nt], 0, 0, 0);
    }
    // Ksum[c] from the same fragments: sum 16 k-values per lane, reduce over g4 groups
    float sm0 = 0.f, sm1 = 0.f;
    #pragma unroll
    for (int ks = 0; ks < 2; ++ks){
      const uint4 u0 = araw[ks][0], u1 = araw[ks][1];
      sm0 += bflo(u0.x)+bfhi(u0.x)+bflo(u0.y)+bfhi(u0.y)
           + bflo(u0.z)+bfhi(u0.z)+bflo(u0.w)+bfhi(u0.w);
      sm1 += bflo(u1.x)+bfhi(u1.x)+bflo(u1.y)+bfhi(u1.y)
           + bflo(u1.z)+bfhi(u1.z)+bflo(u1.w)+bfhi(u1.w);
    }
    sm0 += __shfl_xor(sm0, 16); sm0 += __shfl_xor(sm0, 32);
    sm1 += __shfl_xor(sm1, 16); sm1 += __shfl_xor(sm1, 32);
    if (lane < 16){ ksum[h*32 + l15] = sm0; ksum[h*32 + 16 + l15] = sm1; }
    #pragma unroll
    for (int mt = 0; mt < 2; ++mt)
      #pragma unroll
      for (int nt = 0; nt < 2; ++nt){
        const int v  = nt*16 + l15;
        const int db = (mt*16 + 4*g4)*2;
        *(uint2*)(lds1 + KVO(h, v, db)) =
          pack4(acc[mt][nt][0], acc[mt][nt][1], acc[mt][nt][2], acc[mt][nt][3]);
      }
  }
  __syncthreads();

  // ---- P5: Q = elu(x@Wq)+1 -> lds0 [l][c] (transpose epilogue; V_T dead)
  {
    f32x4 acc[4][2];
    #pragma unroll
    for (int nt = 0; nt < 4; ++nt){ acc[nt][0] = fz; acc[nt][1] = fz; }
    #pragma unroll
    for (int ks = 0; ks < 8; ++ks)
      #pragma unroll
      for (int nt = 0; nt < 4; ++nt){
        const bf16x8 bv = as_bf(wpk[16384 + ((wbn + nt)*8 + ks)*64 + lane]);
        acc[nt][0] = MFMA16(xf[0][ks], bv, acc[nt][0], 0, 0, 0);
        acc[nt][1] = MFMA16(xf[1][ks], bv, acc[nt][1], 0, 0, 0);
      }
    #pragma unroll
    for (int nt = 0; nt < 4; ++nt)
      #pragma unroll
      for (int mt = 0; mt < 2; ++mt){
        float v[4];
        #pragma unroll
        for (int r = 0; r < 4; ++r) v[r] = elup1(acc[nt][mt][r]);
        qtr(v, qi);
        const int l  = rowA + mt*16 + 4*g4 + qi;
        const int cb = (64*wn + nt*16 + 4*qq)*2;
        *(uint2*)(lds0 + AO(l, cb)) = pack4(v[0], v[1], v[2], v[3]);
      }
  }
  // No barrier: Q rows/cols written and consumed by the SAME wave (den + attn A-frags).

  // ---- P6: den[l][h] = eps + Q[l,h*32:]. Ksum[h*32:]  (1 head per lane-half, own rows/heads)
  {
    const int dl = rowA + (lane & 31);
    const int h  = 2*wn + (lane >> 5);
    float s = ATT_EPS;
    #pragma unroll
    for (int j = 0; j < 4; ++j){
      const uint4  qv = *(const uint4*)(lds0 + AO(dl, h*64 + j*16));
      const float4 k0 = *(const float4*)&ksum[h*32 + j*8];
      const float4 k1 = *(const float4*)&ksum[h*32 + j*8 + 4];
      s += bflo(qv.x)*k0.x + bfhi(qv.x)*k0.y + bflo(qv.y)*k0.z + bfhi(qv.y)*k0.w
         + bflo(qv.z)*k1.x + bfhi(qv.z)*k1.y + bflo(qv.w)*k1.z + bfhi(qv.w)*k1.w;
    }
    denb[dl*8 + h] = s;
  }

  // ---- P7: num = Q_h @ KV_h (2 heads/wave), then msg_att = num/den -> lds1 [l][c]
  {
    f32x4 nacc[2][2][2];
    #pragma unroll
    for (int hh = 0; hh < 2; ++hh)
      #pragma unroll
      for (int mt = 0; mt < 2; ++mt)
        #pragma unroll
        for (int nt = 0; nt < 2; ++nt) nacc[hh][mt][nt] = fz;
    #pragma unroll
    for (int hh = 0; hh < 2; ++hh){
      const int h = 2*wn + hh;
      bf16x8 a[2], bb[2];
      #pragma unroll
      for (int mt = 0; mt < 2; ++mt)
        a[mt]  = as_bf(*(const uint4*)(lds0 + AO(rowA + mt*16 + l15, h*64 + g4*16)));
      #pragma unroll
      for (int nt = 0; nt < 2; ++nt)
        bb[nt] = as_bf(*(const uint4*)(lds1 + KVO(h, nt*16 + l15, g4*16)));
      #pragma unroll
      for (int mt = 0; mt < 2; ++mt)
        #pragma unroll
        for (int nt = 0; nt < 2; ++nt)
          nacc[hh][mt][nt] = MFMA16(a[mt], bb[nt], nacc[hh][mt][nt], 0, 0, 0);
    }
    __syncthreads();   // all waves done reading KVT/K_T region before msg_att overwrites lds1
    #pragma unroll
    for (int hh = 0; hh < 2; ++hh){
      const int h = 2*wn + hh;
      #pragma unroll
      for (int mt = 0; mt < 2; ++mt){
        const int   l  = rowA + mt*16 + 4*g4 + qi;
        const float rd = 1.0f / denb[l*8 + h];
        #pragma unroll
        for (int nt = 0; nt < 2; ++nt){
          float v[4];
          #pragma unroll
          for (int r = 0; r < 4; ++r) v[r] = nacc[hh][mt][nt][r];
          qtr(v, qi);
          const int cb = (h*32 + nt*16 + 4*qq)*2;
          *(uint2*)(lds1 + AO(l, cb)) = pack4(v[0]*rd, v[1]*rd, v[2]*rd, v[3]*rd);
        }
      }
    }
  }
  __syncthreads();

  // ---- P8: msg = LN1(msg_att @ Wm) -> lds1 [l][c]
  {
    f32x4 macc[4][2];
    #pragma unroll
    for (int nt = 0; nt < 4; ++nt){ macc[nt][0] = fz; macc[nt][1] = fz; }
    #pragma unroll
    for (int ks = 0; ks < 8; ++ks){
      const bf16x8 a0 = as_bf(*(const uint4*)(lds1 + AO(rowA      + l15, ks*64 + g4*16)));
      const bf16x8 a1 = as_bf(*(const uint4*)(lds1 + AO(rowA + 16 + l15, ks*64 + g4*16)));
      #pragma unroll
      for (int nt = 0; nt < 4; ++nt){
        const bf16x8 bv = as_bf(wpk[24576 + ((wbn + nt)*8 + ks)*64 + lane]);
        macc[nt][0] = MFMA16(a0, bv, macc[nt][0], 0, 0, 0);
        macc[nt][1] = MFMA16(a1, bv, macc[nt][1], 0, 0, 0);
      }
    }
    // LN1 stats: intra-wave (64 cols) via shfl over l15, cross-wn via ps
    float sm[2][4], sv[2][4];
    #pragma unroll
    for (int mt = 0; mt < 2; ++mt)
      #pragma unroll
      for (int r = 0; r < 4; ++r){
        float s = 0.f, q = 0.f;
        #pragma unroll
        for (int nt = 0; nt < 4; ++nt){ const float x = macc[nt][mt][r]; s += x; q += x*x; }
        #pragma unroll
        for (int m = 1; m < 16; m <<= 1){ s += __shfl_xor(s, m); q += __shfl_xor(q, m); }
        sm[mt][r] = s; sv[mt][r] = q;
      }
    if (l15 == 0){
      #pragma unroll
      for (int mt = 0; mt < 2; ++mt)
        #pragma unroll
        for (int r = 0; r < 4; ++r){
          const int row = rowA + mt*16 + 4*g4 + r;
          *(float2*)&ps[(row*4 + wn)*2] = make_float2(sm[mt][r], sv[mt][r]);
        }
    }
    __syncthreads();
    float mean[2][4], rstd[2][4];
    #pragma unroll
    for (int mt = 0; mt < 2; ++mt)
      #pragma unroll
      for (int r = 0; r < 4; ++r){
        const int row = rowA + mt*16 + 4*g4 + r;
        float st = 0.f, qt = 0.f;
        #pragma unroll
        for (int w = 0; w < 4; ++w){
          const float2 p = *(const float2*)&ps[(row*4 + w)*2];
          st += p.x; qt += p.y;
        }
        const float mn = st * (1.f/256.f);
        mean[mt][r] = mn;
        rstd[mt][r] = rsqrtf(qt*(1.f/256.f) - mn*mn + LN_EPS);
      }
    #pragma unroll
    for (int mt = 0; mt < 2; ++mt){
      const int l = rowA + mt*16 + 4*g4 + qi;
      #pragma unroll
      for (int nt = 0; nt < 4; ++nt){
        float v[4];
        #pragma unroll
        for (int r = 0; r < 4; ++r) v[r] = (macc[nt][mt][r] - mean[mt][r]) * rstd[mt][r];
        qtr(v, qi);
        const int c = 64*wn + nt*16 + 4*qq;
        const float4 gg = *(const float4*)(g1v + c);
        const float4 bb = *(const float4*)(b1v + c);
        *(uint2*)(lds1 + AO(l, c*2)) =
          pack4(v[0]*gg.x + bb.x, v[1]*gg.y + bb.y, v[2]*gg.z + bb.z, v[3]*gg.w + bb.w);
      }
    }
  }
  __syncthreads();

  // ---- P9: MLP. h(jt) = relu([x|msg]@W1[:,jt]) -> lds0; oacc += h @ W2[jt]
  f32x4 oacc[4][2];
  #pragma unroll
  for (int nt = 0; nt < 4; ++nt){ oacc[nt][0] = fz; oacc[nt][1] = fz; }

  #pragma unroll
  for (int jt = 0; jt < 2; ++jt){
    f32x4 hacc[4][2];
    #pragma unroll
    for (int nt = 0; nt < 4; ++nt){ hacc[nt][0] = fz; hacc[nt][1] = fz; }
    #pragma unroll
    for (int ks = 0; ks < 8; ++ks)         // x part (k = 0..255), A = held xf
      #pragma unroll
      for (int nt = 0; nt < 4; ++nt){
        const bf16x8 bv = as_bf(wpk[32768 + ((jt*16 + wbn + nt)*16 + ks)*64 + lane]);
        hacc[nt][0] = MFMA16(xf[0][ks], bv, hacc[nt][0], 0, 0, 0);
        hacc[nt][1] = MFMA16(xf[1][ks], bv, hacc[nt][1], 0, 0, 0);
      }
    #pragma unroll
    for (int ks = 0; ks < 8; ++ks){        // msg part (k = 256..511), A from lds1
      const bf16x8 a0 = as_bf(*(const uint4*)(lds1 + AO(rowA      + l15, ks*64 + g4*16)));
      const bf16x8 a1 = as_bf(*(const uint4*)(lds1 + AO(rowA + 16 + l15, ks*64 + g4*16)));
      #pragma unroll
      for (int nt = 0; nt < 4; ++nt){
        const bf16x8 bv = as_bf(wpk[32768 + ((jt*16 + wbn + nt)*16 + 8 + ks)*64 + lane]);
        hacc[nt][0] = MFMA16(a0, bv, hacc[nt][0], 0, 0, 0);
        hacc[nt][1] = MFMA16(a1, bv, hacc[nt][1], 0, 0, 0);
      }
    }
    // relu + transpose -> h in lds0
    #pragma unroll
    for (int mt = 0; mt < 2; ++mt){
      const int l = rowA + mt*16 + 4*g4 + qi;
      #pragma unroll
      for (int nt = 0; nt < 4; ++nt){
        float v[4];
        #pragma unroll
        for (int r = 0; r < 4; ++r) v[r] = fmaxf(hacc[nt][mt][r], 0.f);
        qtr(v, qi);
        const int cb = (64*wn + nt*16 + 4*qq)*2;
        *(uint2*)(lds0 + AO(l, cb)) = pack4(v[0], v[1], v[2], v[3]);
      }
    }
    __syncthreads();
    #pragma unroll
    for (int ks = 0; ks < 8; ++ks){
      const bf16x8 a0 = as_bf(*(const uint4*)(lds0 + AO(rowA      + l15, ks*64 + g4*16)));
      const bf16x8 a1 = as_bf(*(const uint4*)(lds0 + AO(rowA + 16 + l15, ks*64 + g4*16)));
      #pragma unroll
      for (int nt = 0; nt < 4; ++nt){
        const bf16x8 bv = as_bf(wpk[65536 + ((wbn + nt)*16 + jt*8 + ks)*64 + lane]);
        oacc[nt][0] = MFMA16(a0, bv, oacc[nt][0], 0, 0, 0);
        oacc[nt][1] = MFMA16(a1, bv, oacc[nt][1], 0, 0, 0);
      }
    }
    if (jt == 0) __syncthreads();          // protect h overwrite in jt=1
  }

  // ---- P10: LN2 + residual + store
  {
    float sm[2][4], sv[2][4];
    #pragma unroll
    for (int mt = 0; mt < 2; ++mt)
      #pragma unroll
      for (int r = 0; r < 4; ++r){
        float s = 0.f, q = 0.f;
        #pragma unroll
        for (int nt = 0; nt < 4; ++nt){ const float x = oacc[nt][mt][r]; s += x; q += x*x; }
        #pragma unroll
        for (int m = 1; m < 16; m <<= 1){ s += __shfl_xor(s, m); q += __shfl_xor(q, m); }
        sm[mt][r] = s; sv[mt][r] = q;
      }
    // ps last read in P8, >=3 barriers ago -> safe to overwrite
    if (l15 == 0){
      #pragma unroll
      for (int mt = 0; mt < 2; ++mt)
        #pragma unroll
        for (int r = 0; r < 4; ++r){
          const int row = rowA + mt*16 + 4*g4 + r;
          *(float2*)&ps[(row*4 + wn)*2] = make_float2(sm[mt][r], sv[mt][r]);
        }
    }
    __syncthreads();
    float mean[2][4], rstd[2][4];
    #pragma unroll
    for (int mt = 0; mt < 2; ++mt)
      #pragma unroll
      for (int r = 0; r < 4; ++r){
        const int row = rowA + mt*16 + 4*g4 + r;
        float st = 0.f, qt = 0.f;
        #pragma unroll
        for (int w = 0; w < 4; ++w){
          const float2 p = *(const float2*)&ps[(row*4 + w)*2];
          st += p.x; qt += p.y;
        }
        const float mn = st * (1.f/256.f);
        mean[mt][r] = mn;
        rstd[mt][r] = rsqrtf(qt*(1.f/256.f) - mn*mn + LN_EPS);
      }
    #pragma unroll
    for (int mt = 0; mt < 2; ++mt){
      const int l = rowA + mt*16 + 4*g4 + qi;
      const long long row = rowbase + (l >> 3)*240 + (l & 7);
      #pragma unroll
      for (int nt = 0; nt < 4; ++nt){
        float v[4];
        #pragma unroll
        for (int r = 0; r < 4; ++r) v[r] = (oacc[nt][mt][r] - mean[mt][r]) * rstd[mt][r];
        qtr(v, qi);
        const int c = 64*wn + nt*16 + 4*qq;
        const float4 gg = *(const float4*)(g2v + c);
        const float4 bb = *(const float4*)(b2v + c);
        const float4 xu = *(const float4*)(xg + row*256 + c);
        float4 st;
        st.x = v[0]*gg.x + bb.x + xu.x;
        st.y = v[1]*gg.y + bb.y + xu.y;
        st.z = v[2]*gg.z + bb.z + xu.z;
        st.w = v[3]*gg.w + bb.w + xu.w;
        *(float4*)(outg + row*256 + c) = st;
      }
    }
  }
}

extern "C" void kernel_launch(void* const* d_in, const int* in_sizes, int n_in,
                              void* d_out, int out_size, void* d_ws, size_t ws_size,
                              hipStream_t stream) {
  const float* xg = (const float*)d_in[0];
  const float* Wq = (const float*)d_in[1];
  const float* Wk = (const float*)d_in[2];
  const float* Wv = (const float*)d_in[3];
  const float* Wm = (const float*)d_in[4];
  const float* W1 = (const float*)d_in[5];
  const float* W2 = (const float*)d_in[6];
  const float* g1 = (const float*)d_in[7];
  const float* b1 = (const float*)d_in[8];
  const float* g2 = (const float*)d_in[9];
  const float* b2 = (const float*)d_in[10];

  uint4* wpk = (uint4*)d_ws;                       // needs 1.25 MB of workspace
  packw<<<dim3(320), dim3(256), 0, stream>>>(Wk, Wv, Wq, Wm, W1, W2, wpk);

  const int B = in_sizes[0] / (240 * 240 * 256);
  lgattn_mfma<<<dim3(B * 900), dim3(512), 0, stream>>>(xg, wpk, g1, b1, g2, b2, (float*)d_out);
}